// Round 5
// baseline (134.378 us; speedup 1.0000x reference)
//
#include <hip/hip_runtime.h>
#include <hip/hip_bf16.h>

// SoftmaxLossRScore: mean(relu(logsumexp(A @ Neg^T, axis=1) - rowdot(A,P) + r + 1))
// B=2048, N=32768, D=128. bf16 MFMA fused GEMM+sumexp, no [B,N] materialization.
// A pre-scaled by log2(e) so epilogue is a bare v_exp_f32 (exp2).
// R2: XOR-swizzled LDS chunks (chunk ^= row&7) kill frag-read bank conflicts.
// R6: counted-vmcnt ring pipeline (neutral vs R0 -> prefetch depth not the stall).
// R7: occupancy lever, isolated (R5 retry minus its XCD-remap confound):
//     B-tile 64 cols (16 KB/slot), LDS = 3-slot ring = 48 KB -> 3 blocks/CU.
//     Grid 1024 = 16 rowTiles x 64 chunks, NATURAL bid order (rowTile=bid&15:
//     16 consecutive blocks share one B-slice, same locality as R0). 3-deep
//     staging, waits vmcnt(8)/4/0. Theory: all pipes <12% + Occ 18% = TLP
//     starvation at 2 blocks/CU; 3 blocks/CU lets other blocks' waves cover
//     barrier/wait phases.

#define B_ROWS 2048
#define N_NEG  32768
#define DIM    128
#define LOG2E  1.4426950408889634f
#define LN2    0.6931471805599453f

typedef __bf16 bf16x8 __attribute__((ext_vector_type(8)));
typedef float  f32x4  __attribute__((ext_vector_type(4)));

static __device__ inline unsigned short f2bf(float f) {
    union { float f; unsigned u; } v; v.f = f;
    unsigned r = v.u + 0x7FFF + ((v.u >> 16) & 1);   // round-to-nearest-even
    return (unsigned short)(r >> 16);
}

static __device__ inline void load_lds16(const void* g, void* s) {
    __builtin_amdgcn_global_load_lds(
        (const __attribute__((address_space(1))) void*)g,
        (__attribute__((address_space(3))) void*)s,
        16, 0, 0);
}

// ---------- P1 (merged): anchor->bf16*log2e + pos_sim + zero sumexp, neg->bf16
__global__ void prep(const float* __restrict__ anchor,
                     const float* __restrict__ positive,
                     const float* __restrict__ neg,
                     unsigned short* __restrict__ a_bf,
                     unsigned short* __restrict__ n_bf,
                     float* __restrict__ pos_sim,
                     float* __restrict__ sumexp) {
    int t = threadIdx.x;
    if (blockIdx.x < 256) {
        int row = blockIdx.x * 8 + (t >> 5);
        int c4  = (t & 31) * 4;
        const float4 a4 = *(const float4*)(anchor   + row * DIM + c4);
        const float4 p4 = *(const float4*)(positive + row * DIM + c4);
        float dot = a4.x * p4.x + a4.y * p4.y + a4.z * p4.z + a4.w * p4.w;
        ushort4 ab;
        ab.x = f2bf(a4.x * LOG2E); ab.y = f2bf(a4.y * LOG2E);
        ab.z = f2bf(a4.z * LOG2E); ab.w = f2bf(a4.w * LOG2E);
        *(ushort4*)(a_bf + row * DIM + c4) = ab;
        #pragma unroll
        for (int m = 1; m <= 16; m <<= 1) dot += __shfl_xor(dot, m, 64);
        if ((t & 31) == 0) { pos_sim[row] = dot; sumexp[row] = 0.0f; }
    } else {
        int i = (blockIdx.x - 256) * 256 + t;   // float4 index
        #pragma unroll
        for (int k = 0; k < 4; k++) {
            int idx = i + k * (1024 * 256);
            float4 v = *(const float4*)(neg + (size_t)idx * 4);
            ushort4 o;
            o.x = f2bf(v.x); o.y = f2bf(v.y); o.z = f2bf(v.z); o.w = f2bf(v.w);
            *(ushort4*)(n_bf + (size_t)idx * 4) = o;
        }
    }
}

// ---------- main: fused bf16 GEMM + sum(exp2) -------------------------------
// Grid 1024 = 16 row-tiles x 64 chunks (512 cols). Block 256 thr = 4 waves
// (2 row x 2 col). Per t-step: B-tile 64 cols x 128 K in one 16 KB ring slot;
// wave computes 2 j-tiles of 16 cols. A tile (128x128) staged once through
// slots {0,1}, then register-resident af[4][4]. B_t lives in slot (t+2)%3;
// B_{t+3} staged into the slot just consumed. Per-wave load accounting:
// 4 global_load_lds per B tile -> waits vmcnt(8) steady, 4 / 0 at tail.
// LDS rows are 256 B; 16B chunk j of row r holds global chunk j^(r&7)
// (swizzle on the global source address; DMA dest stays linear).
#define CHUNK 512
#define TSTEPS (CHUNK / 64)   // 8

__global__ __launch_bounds__(256, 3) void fused_gemm_lse(
        const unsigned short* __restrict__ A,
        const unsigned short* __restrict__ Nb,
        float* __restrict__ sumexp) {
    __shared__ unsigned short lds[3 * 8192];   // 48 KB ring, 16 KB slots

    const int bid     = blockIdx.x;
    const int rowTile = bid & 15;              // natural order: 16 consecutive
    const int chunk   = bid >> 4;              // bids share one B-slice
    const int wave = threadIdx.x >> 6, lane = threadIdx.x & 63;
    const int wr = wave >> 1, wc = wave & 1;
    const int q = lane >> 4, c = lane & 15;
    const int lrow = lane >> 4;       // staging: row within 4-row group
    const int lchk = lane & 15;       // staging: 16B chunk within row

    const unsigned short* Ag = A + rowTile * (128 * DIM);
    const unsigned short* Bg = Nb + (size_t)(chunk * CHUNK) * DIM;

// stage one 64-row B tile (16 KB) at gbase into ring slot s_ (4 loads/wave):
// wave w covers rows w*16..+15; per-lane global row gets the XOR swizzle,
// LDS dest is wave-uniform (DMA writes base + lane*16, linear).
#define STAGE_B(gbase, s_)                                                     \
    {                                                                          \
        _Pragma("unroll")                                                      \
        for (int i_ = 0; i_ < 4; i_++) {                                       \
            int rloc_ = wave * 16 + i_ * 4;                                    \
            int rg_   = rloc_ + lrow;                                          \
            int gofs_ = rg_ * DIM + ((lchk ^ (rg_ & 7)) << 3);                 \
            load_lds16((gbase) + gofs_, &lds[(s_) * 8192 + rloc_ * DIM]);      \
        }                                                                      \
    }

    // ---- prologue: A (32 KB) -> slots {0,1}, B(0) -> slot 2 ----
    #pragma unroll
    for (int i = 0; i < 8; i++) {
        int rloc = wave * 32 + i * 4;
        int rg   = rloc + lrow;
        int gofs = rg * DIM + ((lchk ^ (rg & 7)) << 3);
        load_lds16(Ag + gofs, &lds[rloc * DIM]);
    }
    STAGE_B(Bg, 2);
    asm volatile("s_waitcnt vmcnt(4)" ::: "memory");   // own A landed, B0 flying
    __builtin_amdgcn_s_barrier();                      // all A in LDS

    // swizzled k-step chunk offsets (ushort units); all fragment rows are
    // == c (mod 8), so this is invariant across t/j/i.
    int swz[4];
    #pragma unroll
    for (int k = 0; k < 4; k++) swz[k] = (((k * 4 + q) ^ (c & 7)) << 3);

    // preload A fragments: wave rows wr*64..+64 (A is contiguous in slots 0,1)
    bf16x8 af[4][4];
    #pragma unroll
    for (int i = 0; i < 4; i++) {
        int row = wr * 64 + i * 16 + c;
        #pragma unroll
        for (int k = 0; k < 4; k++)
            af[i][k] = *(const bf16x8*)&lds[row * DIM + swz[k]];
    }
    asm volatile("s_waitcnt lgkmcnt(0)" ::: "memory");
    __builtin_amdgcn_s_barrier();          // af reads done; slots {0,1} free

    STAGE_B(Bg + 1 * 64 * DIM, 0);         // B1 -> slot 0
    STAGE_B(Bg + 2 * 64 * DIM, 1);         // B2 -> slot 1

    const f32x4 zero4 = {0.f, 0.f, 0.f, 0.f};
    f32x4 sumacc[4] = {zero4, zero4, zero4, zero4};

    int slot = 2;                          // B_t in slot (t+2)%3
    for (int t = 0; t < TSTEPS; t++) {
        // B_t landed; deeper prefetches stay in flight (4 loads per tile/wave)
        if (t < TSTEPS - 2)       asm volatile("s_waitcnt vmcnt(8)" ::: "memory");
        else if (t == TSTEPS - 2) asm volatile("s_waitcnt vmcnt(4)" ::: "memory");
        else                      asm volatile("s_waitcnt vmcnt(0)" ::: "memory");
        __builtin_amdgcn_s_barrier();

        const int sb = slot * 8192;
        #pragma unroll
        for (int j = 0; j < 2; j++) {          // wave cols = wc*32 + j*16
            int brow = wc * 32 + j * 16 + c;
            bf16x8 bf[4];
            #pragma unroll
            for (int k = 0; k < 4; k++)
                bf[k] = *(const bf16x8*)&lds[sb + brow * DIM + swz[k]];
            #pragma unroll
            for (int i = 0; i < 4; i++) {
                f32x4 acc = __builtin_amdgcn_mfma_f32_16x16x32_bf16(af[i][0], bf[0], zero4, 0, 0, 0);
                acc = __builtin_amdgcn_mfma_f32_16x16x32_bf16(af[i][1], bf[1], acc, 0, 0, 0);
                acc = __builtin_amdgcn_mfma_f32_16x16x32_bf16(af[i][2], bf[2], acc, 0, 0, 0);
                acc = __builtin_amdgcn_mfma_f32_16x16x32_bf16(af[i][3], bf[3], acc, 0, 0, 0);
                sumacc[i][0] += __builtin_amdgcn_exp2f(acc[0]);
                sumacc[i][1] += __builtin_amdgcn_exp2f(acc[1]);
                sumacc[i][2] += __builtin_amdgcn_exp2f(acc[2]);
                sumacc[i][3] += __builtin_amdgcn_exp2f(acc[3]);
            }
        }
        asm volatile("s_waitcnt lgkmcnt(0)" ::: "memory");
        __builtin_amdgcn_s_barrier();          // all reads of slot done
        if (t + 3 < TSTEPS)                    // B_{t+3} reuses this slot
            STAGE_B(Bg + (size_t)(t + 3) * 64 * DIM, slot);
        slot = (slot == 2) ? 0 : slot + 1;
    }
#undef STAGE_B

    // per-row combine: reduce 16 column-lanes, atomic into global
    #pragma unroll
    for (int i = 0; i < 4; i++) {
        #pragma unroll
        for (int r = 0; r < 4; r++) {
            float v = sumacc[i][r];
            v += __shfl_xor(v, 1, 64);
            v += __shfl_xor(v, 2, 64);
            v += __shfl_xor(v, 4, 64);
            v += __shfl_xor(v, 8, 64);
            if ((lane & 15) == 0) {
                int row = rowTile * 128 + wr * 64 + i * 16 + q * 4 + r;
                atomicAdd(&sumexp[row], v);
            }
        }
    }
}

// ---------- final: lse, relu, mean -> scalar --------------------------------
__global__ void finalize(const float* __restrict__ sumexp,
                         const float* __restrict__ pos_sim,
                         const float* __restrict__ r_score,
                         float* __restrict__ out) {
    __shared__ float red[4];
    int t = threadIdx.x;
    float acc = 0.0f;
    #pragma unroll
    for (int i = 0; i < 8; i++) {
        int row = t + i * 256;
        float lse  = __log2f(sumexp[row]) * LN2;   // A was pre-scaled by log2e
        float loss = lse - pos_sim[row] + r_score[row] + 1.0f;
        acc += fmaxf(loss, 0.0f);
    }
    #pragma unroll
    for (int m = 1; m <= 32; m <<= 1) acc += __shfl_xor(acc, m, 64);
    if ((t & 63) == 0) red[t >> 6] = acc;
    __syncthreads();
    if (t == 0) out[0] = (red[0] + red[1] + red[2] + red[3]) * (1.0f / (float)B_ROWS);
}

extern "C" void kernel_launch(void* const* d_in, const int* in_sizes, int n_in,
                              void* d_out, int out_size, void* d_ws, size_t ws_size,
                              hipStream_t stream) {
    const float* anchor   = (const float*)d_in[0];
    const float* positive = (const float*)d_in[1];
    const float* negative = (const float*)d_in[2];
    const float* r_score  = (const float*)d_in[3];
    float* out = (float*)d_out;

    char* ws = (char*)d_ws;
    float* sumexp           = (float*)ws;                       // 2048 f32
    float* pos_sim          = (float*)(ws + 8192);              // 2048 f32
    unsigned short* a_bf    = (unsigned short*)(ws + 16384);    // 512 KB
    unsigned short* n_bf    = (unsigned short*)(ws + 16384 + 524288); // 8 MB

    prep<<<1280, 256, 0, stream>>>(anchor, positive, negative, a_bf, n_bf, pos_sim, sumexp);
    fused_gemm_lse<<<1024, 256, 0, stream>>>(a_bf, n_bf, sumexp);
    finalize<<<1, 256, 0, stream>>>(sumexp, pos_sim, r_score, out);
}

// Round 6
// 97.134 us; speedup vs baseline: 1.3834x; 1.3834x over previous
//
#include <hip/hip_runtime.h>
#include <hip/hip_bf16.h>

// SoftmaxLossRScore: mean(relu(logsumexp(A @ Neg^T, axis=1) - rowdot(A,P) + r + 1))
// B=2048, N=32768, D=128. bf16 MFMA fused GEMM+sumexp, no [B,N] materialization.
// A pre-scaled by log2(e) so epilogue is a bare v_exp_f32 (exp2).
// R2: XOR-swizzled LDS chunks (chunk ^= row&7) kill frag-read bank conflicts.
// R6: counted-vmcnt (neutral). R7: 3 blocks/CU (regressed, FETCH 90MB).
// R8: TRAFFIC lever. BM=256 via 512-thread/8-wave block: per-CU wave count,
//     per-wave instruction stream, and sync skeleton are IDENTICAL to R0, but
//     one staged 32KB B-tile now feeds 8 waves instead of 4 -> B passes over
//     L2 halve (16 -> 8; model 144 -> 80 MB). Grid 256 = 8 rowTiles x 32
//     chunks, chunk = bid&31: same-chunk sharers are stride-32 bids == same
//     XCD (round-robin), so each B byte lands in exactly ONE L2; per-XCD
//     working set ~1.5 MB < 4 MB.

#define B_ROWS 2048
#define N_NEG  32768
#define DIM    128
#define LOG2E  1.4426950408889634f
#define LN2    0.6931471805599453f

typedef __bf16 bf16x8 __attribute__((ext_vector_type(8)));
typedef float  f32x4  __attribute__((ext_vector_type(4)));

static __device__ inline unsigned short f2bf(float f) {
    union { float f; unsigned u; } v; v.f = f;
    unsigned r = v.u + 0x7FFF + ((v.u >> 16) & 1);   // round-to-nearest-even
    return (unsigned short)(r >> 16);
}

static __device__ inline void load_lds16(const void* g, void* s) {
    __builtin_amdgcn_global_load_lds(
        (const __attribute__((address_space(1))) void*)g,
        (__attribute__((address_space(3))) void*)s,
        16, 0, 0);
}

// ---------- P1 (merged): anchor->bf16*log2e + pos_sim + zero sumexp, neg->bf16
__global__ void prep(const float* __restrict__ anchor,
                     const float* __restrict__ positive,
                     const float* __restrict__ neg,
                     unsigned short* __restrict__ a_bf,
                     unsigned short* __restrict__ n_bf,
                     float* __restrict__ pos_sim,
                     float* __restrict__ sumexp) {
    int t = threadIdx.x;
    if (blockIdx.x < 256) {
        int row = blockIdx.x * 8 + (t >> 5);
        int c4  = (t & 31) * 4;
        const float4 a4 = *(const float4*)(anchor   + row * DIM + c4);
        const float4 p4 = *(const float4*)(positive + row * DIM + c4);
        float dot = a4.x * p4.x + a4.y * p4.y + a4.z * p4.z + a4.w * p4.w;
        ushort4 ab;
        ab.x = f2bf(a4.x * LOG2E); ab.y = f2bf(a4.y * LOG2E);
        ab.z = f2bf(a4.z * LOG2E); ab.w = f2bf(a4.w * LOG2E);
        *(ushort4*)(a_bf + row * DIM + c4) = ab;
        #pragma unroll
        for (int m = 1; m <= 16; m <<= 1) dot += __shfl_xor(dot, m, 64);
        if ((t & 31) == 0) { pos_sim[row] = dot; sumexp[row] = 0.0f; }
    } else {
        int i = (blockIdx.x - 256) * 256 + t;   // float4 index
        #pragma unroll
        for (int k = 0; k < 4; k++) {
            int idx = i + k * (1024 * 256);
            float4 v = *(const float4*)(neg + (size_t)idx * 4);
            ushort4 o;
            o.x = f2bf(v.x); o.y = f2bf(v.y); o.z = f2bf(v.z); o.w = f2bf(v.w);
            *(ushort4*)(n_bf + (size_t)idx * 4) = o;
        }
    }
}

// ---------- main: fused bf16 GEMM + sum(exp2) -------------------------------
// Grid 256 = 8 row-tiles x 32 N-chunks (chunk = bid&31 -> same-chunk sharers
// co-XCD). Block 512 thr = 8 waves (4 row-groups x 2 col-halves). Block tile
// 256 rows x 1024 cols, inner BN=128. A (256x128 = 64KB) staged once through
// the whole LDS, then register-resident af[4][4] per wave. B tiles (128 cols
// = 32KB) double-buffered in the two 32KB LDS halves. LDS rows are 256 B;
// 16B chunk j of row r holds global chunk j^(r&7) (swizzle applied on the
// global source address; DMA dest stays linear).
#define CHUNK 1024
#define TSTEPS (CHUNK / 128)   // 8

__global__ __launch_bounds__(512, 2) void fused_gemm_lse(
        const unsigned short* __restrict__ A,
        const unsigned short* __restrict__ Nb,
        float* __restrict__ sumexp) {
    __shared__ unsigned short lds[32768];   // 64 KB = 2 x 32 KB halves

    const int bid     = blockIdx.x;
    const int rowTile = bid >> 5;              // 0..7 (256 rows each)
    const int chunk   = bid & 31;              // 0..31 (1024 cols each)
    const int wave = threadIdx.x >> 6, lane = threadIdx.x & 63;
    const int wr = wave >> 1, wc = wave & 1;   // wr 0..3, wc 0..1
    const int q = lane >> 4, c = lane & 15;
    const int lrow = lane >> 4;       // staging: row within 4-row group
    const int lchk = lane & 15;       // staging: 16B chunk within row

    const unsigned short* Ag = A + rowTile * (256 * DIM);
    const unsigned short* Bg = Nb + (size_t)(chunk * CHUNK) * DIM;

    // ---- stage A tile (256 rows, 64 KB) across the whole LDS ----
    #pragma unroll
    for (int i = 0; i < 8; i++) {
        int off = wave * 4096 + i * 512;            // ushort offset, 4 rows
        int r   = (off >> 7) + lrow;                // absolute row 0..255
        int gofs = r * DIM + ((lchk ^ (r & 7)) << 3);
        load_lds16(Ag + gofs, &lds[off]);
    }
    asm volatile("s_waitcnt vmcnt(0)" ::: "memory");
    __syncthreads();

    // swizzled k-step chunk offsets (ushort units); all fragment rows are
    // == c (mod 8), so this is invariant across t/j/i.
    int swz[4];
    #pragma unroll
    for (int k = 0; k < 4; k++) swz[k] = (((k * 4 + q) ^ (c & 7)) << 3);

    // preload A fragments: wave rows wr*64..+64, 4 subtiles x 4 k-steps
    bf16x8 af[4][4];
    #pragma unroll
    for (int i = 0; i < 4; i++) {
        int row = wr * 64 + i * 16 + c;             // 0..255
        #pragma unroll
        for (int k = 0; k < 4; k++)
            af[i][k] = *(const bf16x8*)&lds[row * DIM + swz[k]];
    }
    asm volatile("s_waitcnt lgkmcnt(0)" ::: "memory");
    __syncthreads();   // all af reads done; LDS free for B

    // ---- stage B(0) -> half 0 ----
    #pragma unroll
    for (int i = 0; i < 4; i++) {
        int off = wave * 2048 + i * 512;            // 16 rows/wave
        int r   = (off >> 7) + lrow;                // 0..127
        int gofs = r * DIM + ((lchk ^ (r & 7)) << 3);
        load_lds16(Bg + gofs, &lds[off]);
    }
    asm volatile("s_waitcnt vmcnt(0)" ::: "memory");
    __syncthreads();

    const f32x4 zero4 = {0.f, 0.f, 0.f, 0.f};
    f32x4 sumacc[4] = {zero4, zero4, zero4, zero4};

    for (int t = 0; t < TSTEPS; t++) {
        const int curb = (t & 1) * 16384;           // current half base
        const int nxtb = 16384 - curb;
        if (t + 1 < TSTEPS) {                       // async prefetch B(t+1)
            const unsigned short* Bn = Bg + (size_t)(t + 1) * 128 * DIM;
            #pragma unroll
            for (int i = 0; i < 4; i++) {
                int off = wave * 2048 + i * 512;
                int r   = (off >> 7) + lrow;
                int gofs = r * DIM + ((lchk ^ (r & 7)) << 3);
                load_lds16(Bn + gofs, &lds[nxtb + off]);
            }
        }
        #pragma unroll
        for (int j = 0; j < 4; j++) {               // wave cols = wc*64 + j*16
            int brow = wc * 64 + j * 16 + c;        // 0..127 within tile
            bf16x8 bf[4];
            #pragma unroll
            for (int k = 0; k < 4; k++)
                bf[k] = *(const bf16x8*)&lds[curb + brow * DIM + swz[k]];
            #pragma unroll
            for (int i = 0; i < 4; i++) {
                f32x4 acc = __builtin_amdgcn_mfma_f32_16x16x32_bf16(af[i][0], bf[0], zero4, 0, 0, 0);
                acc = __builtin_amdgcn_mfma_f32_16x16x32_bf16(af[i][1], bf[1], acc, 0, 0, 0);
                acc = __builtin_amdgcn_mfma_f32_16x16x32_bf16(af[i][2], bf[2], acc, 0, 0, 0);
                acc = __builtin_amdgcn_mfma_f32_16x16x32_bf16(af[i][3], bf[3], acc, 0, 0, 0);
                sumacc[i][0] += __builtin_amdgcn_exp2f(acc[0]);
                sumacc[i][1] += __builtin_amdgcn_exp2f(acc[1]);
                sumacc[i][2] += __builtin_amdgcn_exp2f(acc[2]);
                sumacc[i][3] += __builtin_amdgcn_exp2f(acc[3]);
            }
        }
        if (t + 1 < TSTEPS) {
            asm volatile("s_waitcnt vmcnt(0)" ::: "memory");
            __syncthreads();
        }
    }

    // per-row combine: reduce 16 column-lanes, atomic into global
    #pragma unroll
    for (int i = 0; i < 4; i++) {
        #pragma unroll
        for (int r = 0; r < 4; r++) {
            float v = sumacc[i][r];
            v += __shfl_xor(v, 1, 64);
            v += __shfl_xor(v, 2, 64);
            v += __shfl_xor(v, 4, 64);
            v += __shfl_xor(v, 8, 64);
            if ((lane & 15) == 0) {
                int row = rowTile * 256 + wr * 64 + i * 16 + q * 4 + r;
                atomicAdd(&sumexp[row], v);
            }
        }
    }
}

// ---------- final: lse, relu, mean -> scalar --------------------------------
__global__ void finalize(const float* __restrict__ sumexp,
                         const float* __restrict__ pos_sim,
                         const float* __restrict__ r_score,
                         float* __restrict__ out) {
    __shared__ float red[4];
    int t = threadIdx.x;
    float acc = 0.0f;
    #pragma unroll
    for (int i = 0; i < 8; i++) {
        int row = t + i * 256;
        float lse  = __log2f(sumexp[row]) * LN2;   // A was pre-scaled by log2e
        float loss = lse - pos_sim[row] + r_score[row] + 1.0f;
        acc += fmaxf(loss, 0.0f);
    }
    #pragma unroll
    for (int m = 1; m <= 32; m <<= 1) acc += __shfl_xor(acc, m, 64);
    if ((t & 63) == 0) red[t >> 6] = acc;
    __syncthreads();
    if (t == 0) out[0] = (red[0] + red[1] + red[2] + red[3]) * (1.0f / (float)B_ROWS);
}

extern "C" void kernel_launch(void* const* d_in, const int* in_sizes, int n_in,
                              void* d_out, int out_size, void* d_ws, size_t ws_size,
                              hipStream_t stream) {
    const float* anchor   = (const float*)d_in[0];
    const float* positive = (const float*)d_in[1];
    const float* negative = (const float*)d_in[2];
    const float* r_score  = (const float*)d_in[3];
    float* out = (float*)d_out;

    char* ws = (char*)d_ws;
    float* sumexp           = (float*)ws;                       // 2048 f32
    float* pos_sim          = (float*)(ws + 8192);              // 2048 f32
    unsigned short* a_bf    = (unsigned short*)(ws + 16384);    // 512 KB
    unsigned short* n_bf    = (unsigned short*)(ws + 16384 + 524288); // 8 MB

    prep<<<1280, 256, 0, stream>>>(anchor, positive, negative, a_bf, n_bf, pos_sim, sumexp);
    fused_gemm_lse<<<256, 512, 0, stream>>>(a_bf, n_bf, sumexp);
    finalize<<<1, 256, 0, stream>>>(sumexp, pos_sim, r_score, out);
}

// Round 7
// 96.596 us; speedup vs baseline: 1.3911x; 1.0056x over previous
//
#include <hip/hip_runtime.h>
#include <hip/hip_bf16.h>

// SoftmaxLossRScore: mean(relu(logsumexp(A @ Neg^T, axis=1) - rowdot(A,P) + r + 1))
// B=2048, N=32768, D=128. bf16 MFMA fused GEMM+sumexp, no [B,N] materialization.
// A pre-scaled by log2(e) so epilogue is a bare v_exp_f32 (exp2).
// R2: XOR-swizzled LDS chunks (chunk ^= row&7) kill frag-read bank conflicts.
// R6: counted-vmcnt ring (neutral). R7: occupancy (regr). R8: traffic (neutral).
// R9: fine-phase interleave (T3) on the R6 ring -- the one proven lever not yet
//     built. 16 half-tiles of 64 cols (16 KB slot, period-4 ring, tile t in
//     slot (t+2)&3, 3-tile lookahead). Per tile: vmcnt(8)+bar, then 2 phases of
//     {ds_read 4 frags || issue 2 staging loads of t+3 -> bar -> 16 MFMA+exp}.
//     Loads span 6 phase-barriers (never drained in steady state); post-ds
//     barrier clusters waves so MFMA covers other waves' ds/stage issue.

#define B_ROWS 2048
#define N_NEG  32768
#define DIM    128
#define LOG2E  1.4426950408889634f
#define LN2    0.6931471805599453f

typedef __bf16 bf16x8 __attribute__((ext_vector_type(8)));
typedef float  f32x4  __attribute__((ext_vector_type(4)));

static __device__ inline unsigned short f2bf(float f) {
    union { float f; unsigned u; } v; v.f = f;
    unsigned r = v.u + 0x7FFF + ((v.u >> 16) & 1);   // round-to-nearest-even
    return (unsigned short)(r >> 16);
}

static __device__ inline void load_lds16(const void* g, void* s) {
    __builtin_amdgcn_global_load_lds(
        (const __attribute__((address_space(1))) void*)g,
        (__attribute__((address_space(3))) void*)s,
        16, 0, 0);
}

// ---------- P1 (merged): anchor->bf16*log2e + pos_sim + zero sumexp, neg->bf16
__global__ void prep(const float* __restrict__ anchor,
                     const float* __restrict__ positive,
                     const float* __restrict__ neg,
                     unsigned short* __restrict__ a_bf,
                     unsigned short* __restrict__ n_bf,
                     float* __restrict__ pos_sim,
                     float* __restrict__ sumexp) {
    int t = threadIdx.x;
    if (blockIdx.x < 256) {
        int row = blockIdx.x * 8 + (t >> 5);
        int c4  = (t & 31) * 4;
        const float4 a4 = *(const float4*)(anchor   + row * DIM + c4);
        const float4 p4 = *(const float4*)(positive + row * DIM + c4);
        float dot = a4.x * p4.x + a4.y * p4.y + a4.z * p4.z + a4.w * p4.w;
        ushort4 ab;
        ab.x = f2bf(a4.x * LOG2E); ab.y = f2bf(a4.y * LOG2E);
        ab.z = f2bf(a4.z * LOG2E); ab.w = f2bf(a4.w * LOG2E);
        *(ushort4*)(a_bf + row * DIM + c4) = ab;
        #pragma unroll
        for (int m = 1; m <= 16; m <<= 1) dot += __shfl_xor(dot, m, 64);
        if ((t & 31) == 0) { pos_sim[row] = dot; sumexp[row] = 0.0f; }
    } else {
        int i = (blockIdx.x - 256) * 256 + t;   // float4 index
        #pragma unroll
        for (int k = 0; k < 4; k++) {
            int idx = i + k * (1024 * 256);
            float4 v = *(const float4*)(neg + (size_t)idx * 4);
            ushort4 o;
            o.x = f2bf(v.x); o.y = f2bf(v.y); o.z = f2bf(v.z); o.w = f2bf(v.w);
            *(ushort4*)(n_bf + (size_t)idx * 4) = o;
        }
    }
}

// ---------- main: fused bf16 GEMM + sum(exp2) -------------------------------
// Grid 512 = 16 row-tiles x 32 N-chunks, natural bid order (rowTile = bid&15).
// Block 256 thr = 4 waves (2 row x 2 col). Block tile 128 rows x 1024 cols.
// A-frags register-resident (staged once through slots {0,1}).
// LDS 64 KB = 4-slot ring x 16 KB; half-tile t (64 B-rows) in slot (t+2)&3;
// per wave 4 staging loads/tile, 2 issued inside each compute phase, 3-tile
// lookahead -> steady-state wait vmcnt(8) (tiles t+1,t+2 in flight).
// LDS rows are 256 B; 16B chunk j of row r holds global chunk j^(r&7)
// (swizzle on the global source address; DMA dest stays linear).
#define CHUNK 1024
#define NT    (CHUNK / 64)   // 16 half-tiles

__global__ __launch_bounds__(256, 2) void fused_gemm_lse(
        const unsigned short* __restrict__ A,
        const unsigned short* __restrict__ Nb,
        float* __restrict__ sumexp) {
    __shared__ unsigned short lds[4 * 8192];   // 64 KB ring, 16 KB slots

    const int bid     = blockIdx.x;
    const int rowTile = bid & 15;
    const int chunk   = bid >> 4;
    const int wave = threadIdx.x >> 6, lane = threadIdx.x & 63;
    const int wr = wave >> 1, wc = wave & 1;
    const int q = lane >> 4, c = lane & 15;
    const int lrow = lane >> 4;       // staging: row within 4-row group
    const int lchk = lane & 15;       // staging: 16B chunk within row

    const unsigned short* Ag = A + rowTile * (128 * DIM);
    const unsigned short* Bg = Nb + (size_t)(chunk * CHUNK) * DIM;

// stage one 64-row half-tile (16 KB) at gbase into ring slot s_, loads i0..i1
// (each wave covers rows wave*16..+15; 4 loads total, issued in pairs).
#define STAGE_PART(gbase, s_, i0, i1)                                          \
    {                                                                          \
        _Pragma("unroll")                                                      \
        for (int i_ = (i0); i_ <= (i1); i_++) {                                \
            int rloc_ = wave * 16 + i_ * 4;                                    \
            int rg_   = rloc_ + lrow;                                          \
            int gofs_ = rg_ * DIM + ((lchk ^ (rg_ & 7)) << 3);                 \
            load_lds16((gbase) + gofs_, &lds[(s_) * 8192 + rloc_ * DIM]);      \
        }                                                                      \
    }

    // ---- prologue: A (32 KB) -> slots {0,1}; t0 -> slot 2; t1 -> slot 3 ----
    #pragma unroll
    for (int i = 0; i < 8; i++) {
        int rloc = wave * 32 + i * 4;
        int rg   = rloc + lrow;
        int gofs = rg * DIM + ((lchk ^ (rg & 7)) << 3);
        load_lds16(Ag + gofs, &lds[rloc * DIM]);
    }
    STAGE_PART(Bg,            2, 0, 3);
    STAGE_PART(Bg + 64 * DIM, 3, 0, 3);
    asm volatile("s_waitcnt vmcnt(8)" ::: "memory");   // A landed; t0,t1 flying
    __builtin_amdgcn_s_barrier();

    // swizzled k-step chunk offsets (ushort units); all fragment rows are
    // == c (mod 8), so this is invariant across t/p/i.
    int swz[4];
    #pragma unroll
    for (int k = 0; k < 4; k++) swz[k] = (((k * 4 + q) ^ (c & 7)) << 3);

    // preload A fragments: wave rows wr*64..+64 (A contiguous in slots 0,1)
    bf16x8 af[4][4];
    #pragma unroll
    for (int i = 0; i < 4; i++) {
        int row = wr * 64 + i * 16 + c;
        #pragma unroll
        for (int k = 0; k < 4; k++)
            af[i][k] = *(const bf16x8*)&lds[row * DIM + swz[k]];
    }
    asm volatile("s_waitcnt lgkmcnt(0)" ::: "memory");
    __builtin_amdgcn_s_barrier();          // af reads done; slots {0,1} free

    STAGE_PART(Bg + 2 * 64 * DIM, 0, 0, 3);   // t2 -> slot 0 (t3 staged in-loop)

    const f32x4 zero4 = {0.f, 0.f, 0.f, 0.f};
    f32x4 sumacc[4] = {zero4, zero4, zero4, zero4};

    for (int t = 0; t < NT; t++) {
        // tile t's 4 own loads landed; tiles t+1,t+2 (8 loads) stay in flight
        if (t < NT - 2)       asm volatile("s_waitcnt vmcnt(8)" ::: "memory");
        else if (t == NT - 2) asm volatile("s_waitcnt vmcnt(4)" ::: "memory");
        else                  asm volatile("s_waitcnt vmcnt(0)" ::: "memory");
        __builtin_amdgcn_s_barrier();

        const int sb = ((t + 2) & 3) * 8192;                 // read slot
        const int ss = (t + 5) & 3;                          // stage slot (t+3)
        const unsigned short* Bs = Bg + (size_t)(t + 3) * 64 * DIM;

        #pragma unroll
        for (int p = 0; p < 2; p++) {          // 2 phases: 16 cols each
            // phase head: ds_read this phase's B-frags + issue 2 staging loads
            int brow = wc * 32 + p * 16 + c;
            bf16x8 bf[4];
            #pragma unroll
            for (int k = 0; k < 4; k++)
                bf[k] = *(const bf16x8*)&lds[sb + brow * DIM + swz[k]];
            if (t + 3 < NT) STAGE_PART(Bs, ss, p * 2, p * 2 + 1);
            __builtin_amdgcn_s_barrier();      // cluster: all waves issued ds
            // phase body: MFMA + exp (compiler inserts lgkmcnt before use)
            #pragma unroll
            for (int i = 0; i < 4; i++) {
                f32x4 acc = __builtin_amdgcn_mfma_f32_16x16x32_bf16(af[i][0], bf[0], zero4, 0, 0, 0);
                acc = __builtin_amdgcn_mfma_f32_16x16x32_bf16(af[i][1], bf[1], acc, 0, 0, 0);
                acc = __builtin_amdgcn_mfma_f32_16x16x32_bf16(af[i][2], bf[2], acc, 0, 0, 0);
                acc = __builtin_amdgcn_mfma_f32_16x16x32_bf16(af[i][3], bf[3], acc, 0, 0, 0);
                sumacc[i][0] += __builtin_amdgcn_exp2f(acc[0]);
                sumacc[i][1] += __builtin_amdgcn_exp2f(acc[1]);
                sumacc[i][2] += __builtin_amdgcn_exp2f(acc[2]);
                sumacc[i][3] += __builtin_amdgcn_exp2f(acc[3]);
            }
        }
        // no tile-end barrier: next tile's vmcnt+barrier provides the fence
        // before slot (t+2)&3 is overwritten (staging of t+4 happens after it).
    }
#undef STAGE_PART

    // per-row combine: reduce 16 column-lanes, atomic into global
    #pragma unroll
    for (int i = 0; i < 4; i++) {
        #pragma unroll
        for (int r = 0; r < 4; r++) {
            float v = sumacc[i][r];
            v += __shfl_xor(v, 1, 64);
            v += __shfl_xor(v, 2, 64);
            v += __shfl_xor(v, 4, 64);
            v += __shfl_xor(v, 8, 64);
            if ((lane & 15) == 0) {
                int row = rowTile * 128 + wr * 64 + i * 16 + q * 4 + r;
                atomicAdd(&sumexp[row], v);
            }
        }
    }
}

// ---------- final: lse, relu, mean -> scalar --------------------------------
__global__ void finalize(const float* __restrict__ sumexp,
                         const float* __restrict__ pos_sim,
                         const float* __restrict__ r_score,
                         float* __restrict__ out) {
    __shared__ float red[4];
    int t = threadIdx.x;
    float acc = 0.0f;
    #pragma unroll
    for (int i = 0; i < 8; i++) {
        int row = t + i * 256;
        float lse  = __log2f(sumexp[row]) * LN2;   // A was pre-scaled by log2e
        float loss = lse - pos_sim[row] + r_score[row] + 1.0f;
        acc += fmaxf(loss, 0.0f);
    }
    #pragma unroll
    for (int m = 1; m <= 32; m <<= 1) acc += __shfl_xor(acc, m, 64);
    if ((t & 63) == 0) red[t >> 6] = acc;
    __syncthreads();
    if (t == 0) out[0] = (red[0] + red[1] + red[2] + red[3]) * (1.0f / (float)B_ROWS);
}

extern "C" void kernel_launch(void* const* d_in, const int* in_sizes, int n_in,
                              void* d_out, int out_size, void* d_ws, size_t ws_size,
                              hipStream_t stream) {
    const float* anchor   = (const float*)d_in[0];
    const float* positive = (const float*)d_in[1];
    const float* negative = (const float*)d_in[2];
    const float* r_score  = (const float*)d_in[3];
    float* out = (float*)d_out;

    char* ws = (char*)d_ws;
    float* sumexp           = (float*)ws;                       // 2048 f32
    float* pos_sim          = (float*)(ws + 8192);              // 2048 f32
    unsigned short* a_bf    = (unsigned short*)(ws + 16384);    // 512 KB
    unsigned short* n_bf    = (unsigned short*)(ws + 16384 + 524288); // 8 MB

    prep<<<1280, 256, 0, stream>>>(anchor, positive, negative, a_bf, n_bf, pos_sim, sumexp);
    fused_gemm_lse<<<512, 256, 0, stream>>>(a_bf, n_bf, sumexp);
    finalize<<<1, 256, 0, stream>>>(sumexp, pos_sim, r_score, out);
}